// Round 1
// baseline (996.220 us; speedup 1.0000x reference)
//
#include <hip/hip_runtime.h>
#include <hip/hip_bf16.h>

// Problem constants (fixed by the reference)
#define NB 4096
#define NT 200
#define ND 64
#define NH1 128
#define NH2 64

// ws float layout (after 256-byte header holding the dtype flag)
#define WS_WX 0          // 128*128: rows 0..63 = W1b - W1c ; rows 64..127 = W1d
#define WS_WC 16384      // 64*128 : W1a + W1c
#define WS_W2 24576      // 128*64
#define WS_B1 32768      // 128
#define WS_B2 32896      // 64
#define WS_W3 32960      // 64
#define WS_B3 33024      // 1

__device__ __forceinline__ float ldany(const void* p, int i, int bf) {
    if (bf) return __bfloat162float(((const __hip_bfloat16*)p)[i]);
    return ((const float*)p)[i];
}

// ---------------------------------------------------------------------------
// Prep: detect dtype (f32 vs bf16) from W1's bit patterns, then build the
// folded weight arrays in ws (all f32).
// ---------------------------------------------------------------------------
__global__ __launch_bounds__(256) void prep_kernel(
    const void* W1, const void* b1, const void* W2, const void* b2,
    const void* W3, const void* b3, int* flag_out, float* F) {
    __shared__ int votes;
    int tid = threadIdx.x;
    if (tid == 0) votes = 0;
    __syncthreads();
    // Detection: every block scans the same first 256 u32 words of W1.
    // If W1 is packed bf16, the LOW 16 bits of each word are a bf16 value with
    // a glorot-band exponent (or zero). If W1 is f32, the low 16 bits are
    // random mantissa bits (~11% band hit rate).
    {
        const unsigned* w1u = (const unsigned*)W1;
        unsigned w = w1u[tid];
        unsigned lo = w & 0xFFFFu;
        unsigned e = (lo >> 7) & 0xFFu;
        if (lo == 0u || (e >= 96u && e <= 124u)) atomicAdd(&votes, 1);
    }
    __syncthreads();
    int bf = (votes >= 160) ? 1 : 0;
    if (blockIdx.x == 0 && tid == 0) flag_out[0] = bf;

    int gtid = blockIdx.x * blockDim.x + tid;
    int gstride = gridDim.x * blockDim.x;

    // Folded weights:
    //   Wx[k][j]     = W1[64+k][j] - W1[128+k][j]     (k<64)
    //   Wx[64+k][j]  = W1[192+k][j]
    //   Wc[k][j]     = W1[k][j] + W1[128+k][j]
    for (int e = gtid; e < 8192; e += gstride) {
        int k = e >> 7, j = e & 127;
        float w1b = ldany(W1, (64 + k) * 128 + j, bf);
        float w1c = ldany(W1, (128 + k) * 128 + j, bf);
        float w1a = ldany(W1, k * 128 + j, bf);
        float w1d = ldany(W1, (192 + k) * 128 + j, bf);
        F[WS_WX + e] = w1b - w1c;
        F[WS_WX + 8192 + e] = w1d;
        F[WS_WC + e] = w1a + w1c;
        F[WS_W2 + e] = ldany(W2, e, bf);
    }
    for (int e = gtid; e < 128; e += gstride) F[WS_B1 + e] = ldany(b1, e, bf);
    for (int e = gtid; e < 64; e += gstride) {
        F[WS_B2 + e] = ldany(b2, e, bf);
        F[WS_W3 + e] = ldany(W3, e, bf);
    }
    if (gtid == 0) F[WS_B3] = ldany(b3, 0, bf);
}

// ---------------------------------------------------------------------------
// Main: one block per batch element b. 512 threads.
//   h1 = relu(cbias + h @ Weff)      (64 -> 128)
//   h2 = relu(b2 + h1 @ W2)          (128 -> 64)
//   s  = b3 + h2 @ W3, masked softmax over T, out = sum_t w_t * h_t
// ---------------------------------------------------------------------------
__global__ __launch_bounds__(512) void attn_kernel(
    const void* cand, const void* hist, const int* mask,
    const int* flag_p, const float* F, void* out) {
    __shared__ __align__(16) float Weff[64 * 128];   // 32 KB
    __shared__ __align__(16) float W2s[128 * 64];    // 32 KB
    __shared__ float htile[64 * 65];                 // 16.6 KB (reused for h2)
    __shared__ float h1t[64 * 129];                  // 33 KB
    __shared__ float cs[64];
    __shared__ float cbias[128];
    __shared__ float W3s[64];
    __shared__ float b2s[64];
    __shared__ float ss[NT];
    __shared__ float red[512];
    __shared__ float part[8 * 65];
    __shared__ float b3s;

    const int tid = threadIdx.x;
    const int b = blockIdx.x;
    const int bf = flag_p[0];

    if (tid < 64) {
        cs[tid] = ldany(cand, b * 64 + tid, bf);
        W3s[tid] = F[WS_W3 + tid];
        b2s[tid] = F[WS_B2 + tid];
    }
    if (tid == 0) b3s = F[WS_B3];
    __syncthreads();

    // cbias[j] = b1[j] + sum_k c[k] * Wc[k][j]
    if (tid < 128) {
        float a = F[WS_B1 + tid];
        for (int k = 0; k < 64; k++) a = fmaf(cs[k], F[WS_WC + k * 128 + tid], a);
        cbias[tid] = a;
    }
    // Weff[k][j] = Wx[k][j] + c[k] * Wx[64+k][j]
    for (int e = tid; e < 8192; e += 512) {
        int k = e >> 7;
        Weff[e] = fmaf(cs[k], F[WS_WX + 8192 + e], F[WS_WX + e]);
    }
    for (int e = tid; e < 8192; e += 512) W2s[e] = F[WS_W2 + e];
    __syncthreads();

    const int jg = tid & 31, tg = tid >> 5;     // GEMM1: 32 j-groups x 16 t-groups
    const int j0 = jg * 4, t0r = tg * 4;
    const int jg2 = tid & 15, tg2 = tid >> 4;   // GEMM2: 16 j-groups x 32 t-groups
    const int j20 = jg2 * 4, t20 = tg2 * 2;

    for (int tt = 0; tt < 4; tt++) {
        const int tbase = tt * 64;
        const int ntt = (tbase + 64 <= NT) ? 64 : (NT - tbase);
        // stage history tile
        if (bf) {
            const __hip_bfloat16* hp = (const __hip_bfloat16*)hist;
            for (int e = tid; e < ntt * 64; e += 512) {
                int t = e >> 6, k = e & 63;
                htile[t * 65 + k] =
                    __bfloat162float(hp[((long)(b * NT + tbase + t)) * 64 + k]);
            }
        } else {
            const float* hp = (const float*)hist;
            for (int e = tid; e < ntt * 64; e += 512) {
                int t = e >> 6, k = e & 63;
                htile[t * 65 + k] = hp[((long)(b * NT + tbase + t)) * 64 + k];
            }
        }
        __syncthreads();

        // GEMM1: h1[t][j] = relu(cbias[j] + sum_k htile[t][k]*Weff[k][j])
        {
            float acc[4][4];
#pragma unroll
            for (int i = 0; i < 4; i++)
#pragma unroll
                for (int jj = 0; jj < 4; jj++) acc[i][jj] = cbias[j0 + jj];
            for (int k = 0; k < 64; k++) {
                const float4 wv = *(const float4*)&Weff[(k << 7) + j0];
                float x[4];
#pragma unroll
                for (int i = 0; i < 4; i++) x[i] = htile[(t0r + i) * 65 + k];
#pragma unroll
                for (int i = 0; i < 4; i++) {
                    acc[i][0] = fmaf(x[i], wv.x, acc[i][0]);
                    acc[i][1] = fmaf(x[i], wv.y, acc[i][1]);
                    acc[i][2] = fmaf(x[i], wv.z, acc[i][2]);
                    acc[i][3] = fmaf(x[i], wv.w, acc[i][3]);
                }
            }
#pragma unroll
            for (int i = 0; i < 4; i++)
#pragma unroll
                for (int jj = 0; jj < 4; jj++)
                    h1t[(t0r + i) * 129 + j0 + jj] = fmaxf(acc[i][jj], 0.f);
        }
        __syncthreads();

        // GEMM2: h2[t][j] = relu(b2[j] + sum_k h1[t][k]*W2[k][j]) -> htile region
        {
            float a2[2][4];
#pragma unroll
            for (int i = 0; i < 2; i++)
#pragma unroll
                for (int jj = 0; jj < 4; jj++) a2[i][jj] = b2s[j20 + jj];
            for (int k = 0; k < 128; k++) {
                const float4 wv = *(const float4*)&W2s[(k << 6) + j20];
                float x0 = h1t[(t20 + 0) * 129 + k];
                float x1 = h1t[(t20 + 1) * 129 + k];
                a2[0][0] = fmaf(x0, wv.x, a2[0][0]);
                a2[0][1] = fmaf(x0, wv.y, a2[0][1]);
                a2[0][2] = fmaf(x0, wv.z, a2[0][2]);
                a2[0][3] = fmaf(x0, wv.w, a2[0][3]);
                a2[1][0] = fmaf(x1, wv.x, a2[1][0]);
                a2[1][1] = fmaf(x1, wv.y, a2[1][1]);
                a2[1][2] = fmaf(x1, wv.z, a2[1][2]);
                a2[1][3] = fmaf(x1, wv.w, a2[1][3]);
            }
#pragma unroll
            for (int i = 0; i < 2; i++)
#pragma unroll
                for (int jj = 0; jj < 4; jj++)
                    htile[(t20 + i) * 65 + j20 + jj] = fmaxf(a2[i][jj], 0.f);
        }
        __syncthreads();

        // scores
        if (tid < ntt) {
            float s = b3s;
            for (int k = 0; k < 64; k++) s = fmaf(htile[tid * 65 + k], W3s[k], s);
            int m = mask[b * NT + tbase + tid];
            ss[tbase + tid] = (m != 0) ? s : -1e9f;
        }
        __syncthreads();
    }

    // softmax over ss[0..199]
    float v = (tid < NT) ? ss[tid] : -3.0e38f;
    red[tid] = v;
    __syncthreads();
    for (int s = 256; s > 0; s >>= 1) {
        if (tid < s) red[tid] = fmaxf(red[tid], red[tid + s]);
        __syncthreads();
    }
    float M = red[0];
    __syncthreads();
    float p = (tid < NT) ? __expf(ss[tid] - M) : 0.f;
    red[tid] = p;
    __syncthreads();
    for (int s = 256; s > 0; s >>= 1) {
        if (tid < s) red[tid] += red[tid + s];
        __syncthreads();
    }
    float S = red[0];
    if (tid < NT) ss[tid] = p / S;
    __syncthreads();

    // out[b][d] = sum_t w[t] * hist[b][t][d]
    const int d = tid & 63, g = tid >> 6;
    float acc = 0.f;
    if (bf) {
        const __hip_bfloat16* hp = (const __hip_bfloat16*)hist;
        for (int t = g; t < NT; t += 8)
            acc = fmaf(ss[t], __bfloat162float(hp[((long)(b * NT + t)) * 64 + d]), acc);
    } else {
        const float* hp = (const float*)hist;
        for (int t = g; t < NT; t += 8)
            acc = fmaf(ss[t], hp[((long)(b * NT + t)) * 64 + d], acc);
    }
    part[g * 65 + d] = acc;
    __syncthreads();
    if (tid < 64) {
        float o = 0.f;
#pragma unroll
        for (int g2 = 0; g2 < 8; g2++) o += part[g2 * 65 + tid];
        if (bf) ((__hip_bfloat16*)out)[b * 64 + tid] = __float2bfloat16(o);
        else    ((float*)out)[b * 64 + tid] = o;
    }
}

extern "C" void kernel_launch(void* const* d_in, const int* in_sizes, int n_in,
                              void* d_out, int out_size, void* d_ws, size_t ws_size,
                              hipStream_t stream) {
    const void* cand = d_in[0];
    const void* hist = d_in[1];
    const int* mask = (const int*)d_in[2];
    const void* W1 = d_in[3];
    const void* b1 = d_in[4];
    const void* W2 = d_in[5];
    const void* b2 = d_in[6];
    const void* W3 = d_in[7];
    const void* b3 = d_in[8];

    int* flag = (int*)d_ws;
    float* F = (float*)((char*)d_ws + 256);

    prep_kernel<<<32, 256, 0, stream>>>(W1, b1, W2, b2, W3, b3, flag, F);
    attn_kernel<<<NB, 512, 0, stream>>>(cand, hist, mask, flag, F, d_out);
}